// Round 6
// baseline (112.207 us; speedup 1.0000x reference)
//
#include <hip/hip_runtime.h>
#include <math.h>

namespace {
constexpr int RADIUS = 9;
constexpr float EPSV = 1e-5f;
constexpr int N_ = 2, C_ = 64, H_ = 128, W_ = 192;
constexpr int HW  = H_ * W_;            // 24576
constexpr int CHW = C_ * HW;
constexpr size_t OUT1 = (size_t)N_ * 81 * HW;

constexpr int XT = 32, YT = 4;          // spatial tile
constexpr int NIG = 3;                  // i-values per block
constexpr int NT = 384;                 // 4 cg x 3 il x 4 ty x 8 xc
constexpr int MROWS = 6;                // YT + NIG - 1
constexpr int MCOLS = 44;               // cols x0-12 .. x0+31, 11 float4 chunks
constexpr int NCH = 11;
constexpr int ROUNDS = 8;               // 8 planes (2 ch per cg) per round
constexpr int PLF = MROWS * MCOLS;      // 264 floats per plane
constexpr int SLOTS_REAL = 528;         // 8 planes * 66
constexpr int SLOTS_PAD  = 576;         // + 48 pad slots (wave-2 tail, never read)
constexpr int BUF_F = SLOTS_PAD * 4;    // 2304 floats per buffer
constexpr int OFF_INVM = 2 * BUF_F;     // 4608
constexpr int LDS_F = OFF_INVM + PLF;   // 4872 floats = 19488 B
}

__device__ __forceinline__ void load_lds16(const float* g, float* l) {
    __builtin_amdgcn_global_load_lds(
        (const __attribute__((address_space(1))) unsigned int*)(const void*)g,
        (__attribute__((address_space(3))) unsigned int*)(void*)l,
        16, 0, 0);
}

// ---------------------------------------------------------------------------
// Kernel 1: per-pixel inverse channel L2 norms (float4 vectorized)
// ---------------------------------------------------------------------------
__global__ void norms_kernel(const float* __restrict__ img,
                             const float* __restrict__ mp,
                             float* __restrict__ invI,
                             float* __restrict__ invM) {
    int q4 = blockIdx.x * blockDim.x + threadIdx.x;   // [0, N_*HW/4)
    if (q4 >= N_ * HW / 4) return;
    int n = q4 / (HW / 4);
    int rem = q4 - n * (HW / 4);
    const float* pi = img + (size_t)n * CHW + 4 * rem;
    const float* pm = mp  + (size_t)n * CHW + 4 * rem;
    float4 si = {0.f, 0.f, 0.f, 0.f}, sm = {0.f, 0.f, 0.f, 0.f};
#pragma unroll 8
    for (int c = 0; c < C_; ++c) {
        float4 a = *(const float4*)(pi + (size_t)c * HW);
        float4 b = *(const float4*)(pm + (size_t)c * HW);
        si.x = fmaf(a.x, a.x, si.x); si.y = fmaf(a.y, a.y, si.y);
        si.z = fmaf(a.z, a.z, si.z); si.w = fmaf(a.w, a.w, si.w);
        sm.x = fmaf(b.x, b.x, sm.x); sm.y = fmaf(b.y, b.y, sm.y);
        sm.z = fmaf(b.z, b.z, sm.z); sm.w = fmaf(b.w, b.w, sm.w);
    }
    float4 vi, vm;
    vi.x = 1.f / (sqrtf(si.x) + EPSV); vi.y = 1.f / (sqrtf(si.y) + EPSV);
    vi.z = 1.f / (sqrtf(si.z) + EPSV); vi.w = 1.f / (sqrtf(si.w) + EPSV);
    vm.x = 1.f / (sqrtf(sm.x) + EPSV); vm.y = 1.f / (sqrtf(sm.y) + EPSV);
    vm.z = 1.f / (sqrtf(sm.z) + EPSV); vm.w = 1.f / (sqrtf(sm.w) + EPSV);
    *(float4*)(invI + (size_t)n * HW + 4 * rem) = vi;
    *(float4*)(invM + (size_t)n * HW + 4 * rem) = vm;
}

// ---------------------------------------------------------------------------
// Kernel 2: raw correlation, async double-buffered map staging.
//   dotRaw[p,(i,j)] = sum_c map[c, clamp(p+(i,j)-9)] * img[c, p]
//   out_diss = invI[p]*dotRaw ;  out_cos = 1 - invM[p']*out_diss
// Edge (x0==0) replicate-clamp: each thread patches ONLY the slots whose DMA
// it issued itself, after an own-wave vmcnt(0) -> no cross-wave race.
// ---------------------------------------------------------------------------
__global__ __launch_bounds__(NT, 4)
void corr_kernel(const float* __restrict__ img,
                 const float* __restrict__ mp,
                 const float* __restrict__ invIg,
                 const float* __restrict__ invMg,
                 float* __restrict__ out) {
    __shared__ float smem[LDS_F];
    float* const b0 = smem;
    float* const b1 = smem + BUF_F;
    float* const sInvM = smem + OFF_INVM;

    const int bz = blockIdx.z;             // n*3 + ig
    const int n  = bz / NIG;
    const int ig = bz - n * NIG;
    const int y0 = blockIdx.y * YT;
    const int x0 = blockIdx.x * XT;
    const int tid = threadIdx.x;
    const int cg = tid / 96;               // 0..3
    const int t96 = tid - cg * 96;
    const int il = t96 >> 5;               // 0..2
    const int r32 = t96 & 31;
    const int ty = r32 >> 3;               // 0..3
    const int xc = r32 & 7;                // 0..7
    const int ybase = y0 + NIG * ig - RADIUS;
    const bool edge = (x0 == 0);           // block-uniform

    const float* imgN = img + (size_t)n * CHW;
    const float* mapN = mp  + (size_t)n * CHW;

    // ---- per-thread DMA descriptors. slot s -> pl=s/66, r=(s%66)/11, ch=s%11
    //      chnl(ri) = (pl>>1)*16 + ri*2 + (pl&1); LDS float off = 4*s (linear==planar)
    const int l0 = 4 * tid;
    size_t g0; bool isE0 = false; size_t eG0 = 0;
    {
        int pl = tid / 66, rm = tid - 66 * pl, r = rm / 11, ch = rm - 11 * r;
        int gy = min(max(ybase + r, 0), H_ - 1);
        int gx = x0 - 12 + 4 * ch; if (gx < 0) gx = 0;
        size_t base = (size_t)((pl >> 1) * 16 + (pl & 1)) * HW + (size_t)gy * W_;
        g0 = base + gx;
        isE0 = edge && (ch < 3);
        eG0 = base;
    }
    const int l1 = 4 * (NT + tid);
    size_t g1 = 0; bool isE1 = false; size_t eG1 = 0;
    if (tid < 192) {
        int s = NT + tid; if (s > 527) s = 527;     // pad lanes reuse slot 527 src
        int pl = s / 66, rm = s - 66 * pl, r = rm / 11, ch = rm - 11 * r;
        int gy = min(max(ybase + r, 0), H_ - 1);
        int gx = x0 - 12 + 4 * ch; if (gx < 0) gx = 0;
        size_t base = (size_t)((pl >> 1) * 16 + (pl & 1)) * HW + (size_t)gy * W_;
        g1 = base + gx;
        isE1 = edge && (tid < 144) && (ch < 3);
        eG1 = base;
    }

    auto stageAsync = [&](float* nb, int ri) {
        size_t cOff = (size_t)(ri * 2) * HW;
        load_lds16(mapN + g0 + cOff, nb + l0);          // full wave, slots 0..383
        if (tid < 192)                                   // waves 0-2 fully active
            load_lds16(mapN + g1 + cOff, nb + l1);      // slots 384..575 (>=528 pad)
    };

    // ---- stage invM halo once ----
    if (tid < 66) {
        int r = tid / NCH, ch = tid - r * NCH;
        int gy = min(max(ybase + r, 0), H_ - 1);
        int gxs = x0 - 12 + 4 * ch;
        const float* src = invMg + n * HW + (size_t)gy * W_;
        float4 v;
        if (gxs >= 0) v = *(const float4*)(src + gxs);
        else { float s0 = src[0]; v.x = s0; v.y = s0; v.z = s0; v.w = s0; }
        *(float4*)&sInvM[r * MCOLS + 4 * ch] = v;
    }

    float acc[4][RADIUS];
#pragma unroll
    for (int p = 0; p < 4; ++p)
#pragma unroll
        for (int j = 0; j < RADIUS; ++j) acc[p][j] = 0.f;

    const int mapRd = (ty + il) * MCOLS + 4 * xc;
    const float* imgPix = imgN + (size_t)(y0 + ty) * W_ + x0 + 4 * xc;

    auto compute = [&](const float* cur, int ri) {
#pragma unroll
        for (int c = 0; c < 2; ++c) {
            const float* mb = cur + (cg * 2 + c) * PLF + mapRd;
            const float4 a4 = *(const float4*)(imgPix + (size_t)(cg * 16 + ri * 2 + c) * HW);
            float w[16];
            *(float4*)&w[0]  = *(const float4*)(mb);
            *(float4*)&w[4]  = *(const float4*)(mb + 4);
            *(float4*)&w[8]  = *(const float4*)(mb + 8);
            *(float4*)&w[12] = *(const float4*)(mb + 12);
            const float a[4] = {a4.x, a4.y, a4.z, a4.w};
#pragma unroll
            for (int p = 0; p < 4; ++p)
#pragma unroll
                for (int j = 0; j < RADIUS; ++j)
                    acc[p][j] = fmaf(w[p + j + 3], a[p], acc[p][j]);
        }
    };

    // own-slot edge patch: own-wave vmcnt(0) guarantees own DMA landed
    auto edgePatch = [&](float* nb, int ri) {
        float ev0 = 0.f, ev1 = 0.f;
        if (isE0) ev0 = mapN[eG0 + (size_t)(ri * 2) * HW];
        if (isE1) ev1 = mapN[eG1 + (size_t)(ri * 2) * HW];
        asm volatile("s_waitcnt vmcnt(0)" ::: "memory");
        __builtin_amdgcn_sched_barrier(0);
        if (isE0) { float4 v = {ev0, ev0, ev0, ev0}; *(float4*)&nb[l0] = v; }
        if (isE1) { float4 v = {ev1, ev1, ev1, ev1}; *(float4*)&nb[l1] = v; }
    };

    // ---- prologue: stage round 0 ----
    stageAsync(b0, 0);
    if (edge) edgePatch(b0, 0);
    __syncthreads();

    // ---- main 2-phase pipeline ----
#pragma unroll
    for (int ri = 0; ri < ROUNDS; ++ri) {
        float* cur = (ri & 1) ? b1 : b0;
        float* nxt = (ri & 1) ? b0 : b1;
        if (ri + 1 < ROUNDS) stageAsync(nxt, ri + 1);
        compute(cur, ri);
        if (edge && ri + 1 < ROUNDS) edgePatch(nxt, ri + 1);
        __syncthreads();
    }

    // ==== epilogue: serial 4-way c-reduce in LDS (overlay on b0/b1) ====
    float* mine = &smem[t96 * 44];          // 96 x 44 floats = 4224 <= 4608
    if (cg == 3) {
#pragma unroll
        for (int j = 0; j < RADIUS; ++j) {
            float4 v = {acc[0][j], acc[1][j], acc[2][j], acc[3][j]};
            *(float4*)&mine[4 * j] = v;
        }
    }
    __syncthreads();
    if (cg == 2) {
#pragma unroll
        for (int j = 0; j < RADIUS; ++j) {
            float4 v = *(const float4*)&mine[4 * j];
            v.x += acc[0][j]; v.y += acc[1][j]; v.z += acc[2][j]; v.w += acc[3][j];
            *(float4*)&mine[4 * j] = v;
        }
    }
    __syncthreads();
    if (cg == 1) {
#pragma unroll
        for (int j = 0; j < RADIUS; ++j) {
            float4 v = *(const float4*)&mine[4 * j];
            v.x += acc[0][j]; v.y += acc[1][j]; v.z += acc[2][j]; v.w += acc[3][j];
            *(float4*)&mine[4 * j] = v;
        }
    }
    __syncthreads();
    if (cg == 0) {
#pragma unroll
        for (int j = 0; j < RADIUS; ++j) {
            float4 v = *(const float4*)&mine[4 * j];
            v.x += acc[0][j]; v.y += acc[1][j]; v.z += acc[2][j]; v.w += acc[3][j];
            *(float4*)&mine[4 * j] = v;
        }
    }
    __syncthreads();

    // ---- all threads store a disjoint j-subset of this (il, px) slot ----
    const int y = y0 + ty;
    const int xb = x0 + 4 * xc;
    float4 vI = *(const float4*)(invIg + n * HW + (size_t)y * W_ + xb);
    const int i = NIG * ig + il;
    float* ocB = out + (size_t)n * 81 * HW + (size_t)y * W_ + xb;
    const int j0  = (cg == 0) ? 0 : (cg == 1) ? 3 : (cg == 2) ? 5 : 7;
    const int cnt = (cg == 0) ? 3 : 2;
    const float* wmB = &sInvM[(ty + il) * MCOLS + 4 * xc + 3];
    for (int jj = 0; jj < cnt; ++jj) {
        int j = j0 + jj;
        float4 s = *(const float4*)&mine[4 * j];
        float4 vd, vc;
        vd.x = s.x * vI.x; vd.y = s.y * vI.y;
        vd.z = s.z * vI.z; vd.w = s.w * vI.w;
        vc.x = 1.f - vd.x * wmB[j + 0];
        vc.y = 1.f - vd.y * wmB[j + 1];
        vc.z = 1.f - vd.z * wmB[j + 2];
        vc.w = 1.f - vd.w * wmB[j + 3];
        size_t o = (size_t)(i * RADIUS + j) * HW;
        *(float4*)(ocB + o) = vc;
        *(float4*)(ocB + OUT1 + o) = vd;
    }
}

extern "C" void kernel_launch(void* const* d_in, const int* in_sizes, int n_in,
                              void* d_out, int out_size, void* d_ws, size_t ws_size,
                              hipStream_t stream) {
    const float* img = (const float*)d_in[0];
    const float* mp  = (const float*)d_in[1];
    float* out  = (float*)d_out;
    float* invI = (float*)d_ws;
    float* invM = invI + N_ * HW;

    int nq4 = N_ * HW / 4;
    norms_kernel<<<(nq4 + 255) / 256, 256, 0, stream>>>(img, mp, invI, invM);

    dim3 grid(W_ / XT, H_ / YT, N_ * NIG);   // 6 x 32 x 6 = 1152 blocks
    corr_kernel<<<grid, NT, 0, stream>>>(img, mp, invI, invM, out);
}

// Round 7
// 110.510 us; speedup vs baseline: 1.0154x; 1.0154x over previous
//
#include <hip/hip_runtime.h>
#include <math.h>

namespace {
constexpr int RADIUS = 9;
constexpr float EPSV = 1e-5f;
constexpr int N_ = 2, C_ = 64, H_ = 128, W_ = 192;
constexpr int HW  = H_ * W_;            // 24576
constexpr int CHW = C_ * HW;
constexpr size_t OUT1 = (size_t)N_ * 81 * HW;

constexpr int XT = 32, YT = 4;          // spatial tile
constexpr int NIG = 3;                  // i-values per block
constexpr int NT = 384;                 // 4 cg x 3 il x 4 ty x 8 xc
constexpr int MROWS = 6;                // YT + NIG - 1
constexpr int MCOLS = 44;               // cols x0-12 .. x0+31 (11 float4 chunks)
constexpr int NCH = 11;
constexpr int ROUNDS = 8;               // 8 planes (2 ch per cg) per round
constexpr int PLF = MROWS * MCOLS;      // 264 floats per plane
constexpr int SLOTS = 528;              // 8 planes * 66 chunks
constexpr int BUF_F = SLOTS * 4;        // 2112 floats per buffer
constexpr int OFF_INVM = 2 * BUF_F;     // 4224
constexpr int LDS_F = OFF_INVM + PLF;   // 4488 floats = 17952 B
}

// pure helper: load one staged map chunk for round ri (replicate-clamp splat)
__device__ __forceinline__ float4 ldmap(const float* __restrict__ mapN,
                                        size_t g, bool bc, int ri) {
    float4 v = *(const float4*)(mapN + g + (size_t)(2 * ri) * HW);
    if (bc) { v.y = v.x; v.z = v.x; v.w = v.x; }
    return v;
}

// ---------------------------------------------------------------------------
// Kernel 1: per-pixel inverse channel L2 norms (float4 vectorized)
// ---------------------------------------------------------------------------
__global__ void norms_kernel(const float* __restrict__ img,
                             const float* __restrict__ mp,
                             float* __restrict__ invI,
                             float* __restrict__ invM) {
    int q4 = blockIdx.x * blockDim.x + threadIdx.x;   // [0, N_*HW/4)
    if (q4 >= N_ * HW / 4) return;
    int n = q4 / (HW / 4);
    int rem = q4 - n * (HW / 4);
    const float* pi = img + (size_t)n * CHW + 4 * rem;
    const float* pm = mp  + (size_t)n * CHW + 4 * rem;
    float4 si = {0.f, 0.f, 0.f, 0.f}, sm = {0.f, 0.f, 0.f, 0.f};
#pragma unroll 8
    for (int c = 0; c < C_; ++c) {
        float4 a = *(const float4*)(pi + (size_t)c * HW);
        float4 b = *(const float4*)(pm + (size_t)c * HW);
        si.x = fmaf(a.x, a.x, si.x); si.y = fmaf(a.y, a.y, si.y);
        si.z = fmaf(a.z, a.z, si.z); si.w = fmaf(a.w, a.w, si.w);
        sm.x = fmaf(b.x, b.x, sm.x); sm.y = fmaf(b.y, b.y, sm.y);
        sm.z = fmaf(b.z, b.z, sm.z); sm.w = fmaf(b.w, b.w, sm.w);
    }
    float4 vi, vm;
    vi.x = 1.f / (sqrtf(si.x) + EPSV); vi.y = 1.f / (sqrtf(si.y) + EPSV);
    vi.z = 1.f / (sqrtf(si.z) + EPSV); vi.w = 1.f / (sqrtf(si.w) + EPSV);
    vm.x = 1.f / (sqrtf(sm.x) + EPSV); vm.y = 1.f / (sqrtf(sm.y) + EPSV);
    vm.z = 1.f / (sqrtf(sm.z) + EPSV); vm.w = 1.f / (sqrtf(sm.w) + EPSV);
    *(float4*)(invI + (size_t)n * HW + 4 * rem) = vi;
    *(float4*)(invM + (size_t)n * HW + 4 * rem) = vm;
}

// ---------------------------------------------------------------------------
// Kernel 2: raw correlation, reg-staged double-buffered map (T14 split:
// issue loads early -> compute -> ds_write late -> barrier).
//   dotRaw[p,(i,j)] = sum_c map[c, clamp(p+(i,j)-9)] * img[c, p]
//   out_diss = invI[p]*dotRaw ;  out_cos = 1 - invM[p']*out_diss
// ---------------------------------------------------------------------------
__global__ __launch_bounds__(NT, 4)
void corr_kernel(const float* __restrict__ img,
                 const float* __restrict__ mp,
                 const float* __restrict__ invIg,
                 const float* __restrict__ invMg,
                 float* __restrict__ out) {
    __shared__ float smem[LDS_F];
    float* const b0 = smem;
    float* const b1 = smem + BUF_F;
    float* const sInvM = smem + OFF_INVM;

    const int bz = blockIdx.z;             // n*3 + ig
    const int n  = bz / NIG;
    const int ig = bz - n * NIG;
    const int y0 = blockIdx.y * YT;
    const int x0 = blockIdx.x * XT;
    const int tid = threadIdx.x;
    const int cg = tid / 96;               // 0..3
    const int t96 = tid - cg * 96;
    const int il = t96 >> 5;               // 0..2
    const int r32 = t96 & 31;
    const int ty = r32 >> 3;               // 0..3
    const int xc = r32 & 7;                // 0..7
    const int ybase = y0 + NIG * ig - RADIUS;

    const float* imgN = img + (size_t)n * CHW;
    const float* mapN = mp  + (size_t)n * CHW;

    // ---- staging descriptors: slot s -> pl=s/66, r=(s%66)/11, ch=s%11
    //      chnl(ri) = (pl>>1)*16 + 2*ri + (pl&1); LDS float off = 4*s
    const int lA = 4 * tid;
    size_t gA; bool bcA;
    {
        int pl = tid / 66, rm = tid - 66 * pl, r = rm / 11, ch = rm - 11 * r;
        int gy = min(max(ybase + r, 0), H_ - 1);
        int gxs = x0 - 12 + 4 * ch;
        bcA = (gxs < 0); if (gxs < 0) gxs = 0;      // chunk fully OOB -> splat col0
        gA = (size_t)((pl >> 1) * 16 + (pl & 1)) * HW + (size_t)gy * W_ + gxs;
    }
    const bool hasB = (tid < 144);
    const int lB = 4 * (NT + tid);
    size_t gB = 0; bool bcB = false;
    if (hasB) {
        int s = NT + tid;
        int pl = s / 66, rm = s - 66 * pl, r = rm / 11, ch = rm - 11 * r;
        int gy = min(max(ybase + r, 0), H_ - 1);
        int gxs = x0 - 12 + 4 * ch;
        bcB = (gxs < 0); if (gxs < 0) gxs = 0;
        gB = (size_t)((pl >> 1) * 16 + (pl & 1)) * HW + (size_t)gy * W_ + gxs;
    }

    // ---- stage invM halo once ----
    if (tid < 66) {
        int r = tid / NCH, ch = tid - r * NCH;
        int gy = min(max(ybase + r, 0), H_ - 1);
        int gxs = x0 - 12 + 4 * ch;
        const float* src = invMg + n * HW + (size_t)gy * W_;
        float4 v;
        if (gxs >= 0) v = *(const float4*)(src + gxs);
        else { float s0 = src[0]; v.x = s0; v.y = s0; v.z = s0; v.w = s0; }
        *(float4*)&sInvM[r * MCOLS + 4 * ch] = v;
    }

    float acc[4][RADIUS];
#pragma unroll
    for (int p = 0; p < 4; ++p)
#pragma unroll
        for (int j = 0; j < RADIUS; ++j) acc[p][j] = 0.f;

    const int mapRd = (ty + il) * MCOLS + 4 * xc;
    const float* imgPix = imgN + (size_t)(y0 + ty) * W_ + x0 + 4 * xc;

    // ---- prologue: stage round 0 synchronously ----
    {
        float4 vA = ldmap(mapN, gA, bcA, 0);
        *(float4*)&b0[lA] = vA;
        if (hasB) {
            float4 vB = ldmap(mapN, gB, bcB, 0);
            *(float4*)&b1[0] = *(float4*)&b1[0];   // no-op keep layout simple
            *(float4*)&b0[lB] = vB;
        }
    }
    __syncthreads();

    // ---- main pipeline: load(ri+1)->regs, compute(ri), ds_write(ri+1), barrier
#pragma unroll
    for (int ri = 0; ri < ROUNDS; ++ri) {
        float* cur = (ri & 1) ? b1 : b0;
        float* nxt = (ri & 1) ? b0 : b1;
        float4 nA, nB;
        if (ri + 1 < ROUNDS) {
            nA = ldmap(mapN, gA, bcA, ri + 1);
            if (hasB) nB = ldmap(mapN, gB, bcB, ri + 1);
        }
        // ---- compute: 2 channels for this cg ----
#pragma unroll
        for (int c = 0; c < 2; ++c) {
            const float* mb = cur + (cg * 2 + c) * PLF + mapRd;
            const float4 a4 = *(const float4*)(imgPix + (size_t)(cg * 16 + ri * 2 + c) * HW);
            float w[16];
            *(float4*)&w[0]  = *(const float4*)(mb);
            *(float4*)&w[4]  = *(const float4*)(mb + 4);
            *(float4*)&w[8]  = *(const float4*)(mb + 8);
            *(float4*)&w[12] = *(const float4*)(mb + 12);
            const float a[4] = {a4.x, a4.y, a4.z, a4.w};
#pragma unroll
            for (int p = 0; p < 4; ++p)
#pragma unroll
                for (int j = 0; j < RADIUS; ++j)
                    acc[p][j] = fmaf(w[p + j + 3], a[p], acc[p][j]);
        }
        if (ri + 1 < ROUNDS) {
            *(float4*)&nxt[lA] = nA;
            if (hasB) *(float4*)&nxt[lB] = nB;
        }
        __syncthreads();
    }

    // ==== epilogue: serial 4-way c-reduce in LDS (overlay on b0/b1) ====
    float* mine = &smem[t96 * 44];          // 96 x 44 floats = 4224 = 2*BUF_F
    if (cg == 3) {
#pragma unroll
        for (int j = 0; j < RADIUS; ++j) {
            float4 v = {acc[0][j], acc[1][j], acc[2][j], acc[3][j]};
            *(float4*)&mine[4 * j] = v;
        }
    }
    __syncthreads();
    if (cg == 2) {
#pragma unroll
        for (int j = 0; j < RADIUS; ++j) {
            float4 v = *(const float4*)&mine[4 * j];
            v.x += acc[0][j]; v.y += acc[1][j]; v.z += acc[2][j]; v.w += acc[3][j];
            *(float4*)&mine[4 * j] = v;
        }
    }
    __syncthreads();
    if (cg == 1) {
#pragma unroll
        for (int j = 0; j < RADIUS; ++j) {
            float4 v = *(const float4*)&mine[4 * j];
            v.x += acc[0][j]; v.y += acc[1][j]; v.z += acc[2][j]; v.w += acc[3][j];
            *(float4*)&mine[4 * j] = v;
        }
    }
    __syncthreads();
    if (cg == 0) {
#pragma unroll
        for (int j = 0; j < RADIUS; ++j) {
            float4 v = *(const float4*)&mine[4 * j];
            v.x += acc[0][j]; v.y += acc[1][j]; v.z += acc[2][j]; v.w += acc[3][j];
            *(float4*)&mine[4 * j] = v;
        }
    }
    __syncthreads();

    // ---- all threads store a disjoint j-subset of this (il, px) slot ----
    const int y = y0 + ty;
    const int xb = x0 + 4 * xc;
    float4 vI = *(const float4*)(invIg + n * HW + (size_t)y * W_ + xb);
    const int i = NIG * ig + il;
    float* ocB = out + (size_t)n * 81 * HW + (size_t)y * W_ + xb;
    const int j0  = (cg == 0) ? 0 : (cg == 1) ? 3 : (cg == 2) ? 5 : 7;
    const int cnt = (cg == 0) ? 3 : 2;
    const float* wmB = &sInvM[(ty + il) * MCOLS + 4 * xc + 3];
    for (int jj = 0; jj < cnt; ++jj) {
        int j = j0 + jj;
        float4 s = *(const float4*)&mine[4 * j];
        float4 vd, vc;
        vd.x = s.x * vI.x; vd.y = s.y * vI.y;
        vd.z = s.z * vI.z; vd.w = s.w * vI.w;
        vc.x = 1.f - vd.x * wmB[j + 0];
        vc.y = 1.f - vd.y * wmB[j + 1];
        vc.z = 1.f - vd.z * wmB[j + 2];
        vc.w = 1.f - vd.w * wmB[j + 3];
        size_t o = (size_t)(i * RADIUS + j) * HW;
        *(float4*)(ocB + o) = vc;
        *(float4*)(ocB + OUT1 + o) = vd;
    }
}

extern "C" void kernel_launch(void* const* d_in, const int* in_sizes, int n_in,
                              void* d_out, int out_size, void* d_ws, size_t ws_size,
                              hipStream_t stream) {
    const float* img = (const float*)d_in[0];
    const float* mp  = (const float*)d_in[1];
    float* out  = (float*)d_out;
    float* invI = (float*)d_ws;
    float* invM = invI + N_ * HW;

    int nq4 = N_ * HW / 4;
    norms_kernel<<<(nq4 + 255) / 256, 256, 0, stream>>>(img, mp, invI, invM);

    dim3 grid(W_ / XT, H_ / YT, N_ * NIG);   // 6 x 32 x 6 = 1152 blocks
    corr_kernel<<<grid, NT, 0, stream>>>(img, mp, invI, invM, out);
}

// Round 8
// 67.900 us; speedup vs baseline: 1.6525x; 1.6275x over previous
//
#include <hip/hip_runtime.h>
#include <math.h>

namespace {
constexpr int RADIUS = 9;
constexpr float EPSV = 1e-5f;
constexpr int N_ = 2, C_ = 64, H_ = 128, W_ = 192;
constexpr int HW  = H_ * W_;            // 24576
constexpr int CHW = C_ * HW;
constexpr size_t OUT1 = (size_t)N_ * 81 * HW;

constexpr int XT = 32, YT = 4;          // spatial tile
constexpr int NIG = 3;                  // i-values per block
constexpr int NT = 384;                 // 4 cg x 3 il x 4 ty x 8 xc
constexpr int MROWS = 6;                // YT + NIG - 1
constexpr int MCOLS = 44;               // cols x0-12 .. x0+31 (11 float4 chunks)
constexpr int NCH = 11;
constexpr int ROUNDS = 8;               // 8 planes (2 ch per cg) per round
constexpr int PLF = MROWS * MCOLS;      // 264 floats per plane
constexpr int SLOTS_PAD = 576;          // 528 real + 48 pad (wave-2 tail, never read)
constexpr int BUF_F = SLOTS_PAD * 4;    // 2304 floats per buffer
constexpr int OFF_INVM = 2 * BUF_F;     // 4608
constexpr int LDS_F = OFF_INVM + PLF;   // 4872 floats = 19488 B
}

__device__ __forceinline__ void load_lds16(const float* g, float* l) {
    __builtin_amdgcn_global_load_lds(
        (const __attribute__((address_space(1))) unsigned int*)(const void*)g,
        (__attribute__((address_space(3))) unsigned int*)(void*)l,
        16, 0, 0);
}

// ---------------------------------------------------------------------------
// Kernel 1: per-pixel inverse channel L2 norms + left-edge replicate strip
//   strip[(n*C + c)*H + y][0..3] = map[n,c,y,0]  (splat of column 0)
// ---------------------------------------------------------------------------
__global__ void norms_kernel(const float* __restrict__ img,
                             const float* __restrict__ mp,
                             float* __restrict__ invI,
                             float* __restrict__ invM,
                             float* __restrict__ strip) {
    int q = blockIdx.x * blockDim.x + threadIdx.x;   // [0, N_*HW)
    if (q >= N_ * HW) return;
    int n = q / HW;
    int rem = q - n * HW;
    int y = rem / W_;
    int x = rem - y * W_;
    const float* pi = img + (size_t)n * CHW + rem;
    const float* pm = mp  + (size_t)n * CHW + rem;
    const bool e = (x == 0);
    float* sp = strip + ((size_t)n * C_ * H_ + y) * 4;   // + c*H_*4
    float si = 0.f, sm = 0.f;
#pragma unroll 8
    for (int c = 0; c < C_; ++c) {
        float a = pi[(size_t)c * HW];
        float b = pm[(size_t)c * HW];
        si = fmaf(a, a, si);
        sm = fmaf(b, b, sm);
        if (e) { float4 v = {b, b, b, b}; *(float4*)(sp + (size_t)c * H_ * 4) = v; }
    }
    invI[q] = 1.f / (sqrtf(si) + EPSV);
    invM[q] = 1.f / (sqrtf(sm) + EPSV);
}

// ---------------------------------------------------------------------------
// Kernel 2: raw correlation; async double-buffered map staging via
// global_load_lds. Left-OOB chunks source from the replicate strip ->
// no patching, no extra waits.
//   dotRaw[p,(i,j)] = sum_c map[c, clamp(p+(i,j)-9)] * img[c, p]
//   out_diss = invI[p]*dotRaw ;  out_cos = 1 - invM[p']*out_diss
// ---------------------------------------------------------------------------
__global__ __launch_bounds__(NT)
void corr_kernel(const float* __restrict__ img,
                 const float* __restrict__ mp,
                 const float* __restrict__ invIg,
                 const float* __restrict__ invMg,
                 const float* __restrict__ strip,
                 float* __restrict__ out) {
    __shared__ float smem[LDS_F];
    float* const b0 = smem;
    float* const b1 = smem + BUF_F;
    float* const sInvM = smem + OFF_INVM;

    const int bz = blockIdx.z;             // n*3 + ig
    const int n  = bz / NIG;
    const int ig = bz - n * NIG;
    const int y0 = blockIdx.y * YT;
    const int x0 = blockIdx.x * XT;
    const int tid = threadIdx.x;
    const int cg = tid / 96;               // 0..3
    const int t96 = tid - cg * 96;
    const int il = t96 >> 5;               // 0..2
    const int r32 = t96 & 31;
    const int ty = r32 >> 3;               // 0..3
    const int xc = r32 & 7;                // 0..7
    const int ybase = y0 + NIG * ig - RADIUS;

    const float* imgN = img + (size_t)n * CHW;
    const float* mapN = mp  + (size_t)n * CHW;

    // ---- DMA descriptors. slot s -> pl=s/66, r=(s%66)/11, ch=s%11
    //      round-ri channel for plane pl: (pl>>1)*16 + 2*ri + (pl&1)
    //      LDS float offset = 4*s (slot-linear, lane-contiguous per wave)
    const int lA = 4 * tid;
    const float* pA; int sA;
    {
        int pl = tid / 66, rm = tid - 66 * pl, r = rm / 11, ch = rm - 11 * r;
        int ch0 = (pl >> 1) * 16 + (pl & 1);
        int gy = min(max(ybase + r, 0), H_ - 1);
        int gxs = x0 - 12 + 4 * ch;
        if (gxs < 0) {                      // fully-left-OOB chunk -> strip
            pA = strip + ((size_t)(n * C_ + ch0) * H_ + gy) * 4;
            sA = 2 * H_ * 4;
        } else {
            pA = mapN + (size_t)ch0 * HW + (size_t)gy * W_ + gxs;
            sA = 2 * HW;
        }
    }
    const int lB = 4 * (NT + tid);
    const float* pB = nullptr; int sB = 0;
    if (tid < 192) {                        // waves 0-2, fully active
        int s = NT + tid; if (s > 527) s = 527;   // pad lanes reuse slot 527 src
        int pl = s / 66, rm = s - 66 * pl, r = rm / 11, ch = rm - 11 * r;
        int ch0 = (pl >> 1) * 16 + (pl & 1);
        int gy = min(max(ybase + r, 0), H_ - 1);
        int gxs = x0 - 12 + 4 * ch;
        if (gxs < 0) {
            pB = strip + ((size_t)(n * C_ + ch0) * H_ + gy) * 4;
            sB = 2 * H_ * 4;
        } else {
            pB = mapN + (size_t)ch0 * HW + (size_t)gy * W_ + gxs;
            sB = 2 * HW;
        }
    }

    // ---- stage invM halo once ----
    if (tid < 66) {
        int r = tid / NCH, ch = tid - r * NCH;
        int gy = min(max(ybase + r, 0), H_ - 1);
        int gxs = x0 - 12 + 4 * ch;
        const float* src = invMg + n * HW + (size_t)gy * W_;
        float4 v;
        if (gxs >= 0) v = *(const float4*)(src + gxs);
        else { float s0 = src[0]; v.x = s0; v.y = s0; v.z = s0; v.w = s0; }
        *(float4*)&sInvM[r * MCOLS + 4 * ch] = v;
    }

    float acc[4][RADIUS];
#pragma unroll
    for (int p = 0; p < 4; ++p)
#pragma unroll
        for (int j = 0; j < RADIUS; ++j) acc[p][j] = 0.f;

    const int mapRd = (ty + il) * MCOLS + 4 * xc;
    const float* imgPix = imgN + (size_t)(y0 + ty) * W_ + x0 + 4 * xc;

    // ---- prologue: DMA round 0 into b0; barrier drains it ----
    load_lds16(pA, b0 + lA);
    if (tid < 192) load_lds16(pB, b0 + lB);
    __syncthreads();

    // ---- 2-phase pipeline: DMA(ri+1) -> compute(ri) -> barrier(drain) ----
#pragma unroll
    for (int ri = 0; ri < ROUNDS; ++ri) {
        float* cur = (ri & 1) ? b1 : b0;
        float* nxt = (ri & 1) ? b0 : b1;
        if (ri + 1 < ROUNDS) {
            load_lds16(pA + (size_t)(ri + 1) * sA, nxt + lA);
            if (tid < 192) load_lds16(pB + (size_t)(ri + 1) * sB, nxt + lB);
        }
#pragma unroll
        for (int c = 0; c < 2; ++c) {
            const float* mb = cur + (cg * 2 + c) * PLF + mapRd;
            const float4 a4 = *(const float4*)(imgPix + (size_t)(cg * 16 + ri * 2 + c) * HW);
            float w[16];
            *(float4*)&w[0]  = *(const float4*)(mb);
            *(float4*)&w[4]  = *(const float4*)(mb + 4);
            *(float4*)&w[8]  = *(const float4*)(mb + 8);
            *(float4*)&w[12] = *(const float4*)(mb + 12);
            const float a[4] = {a4.x, a4.y, a4.z, a4.w};
#pragma unroll
            for (int p = 0; p < 4; ++p)
#pragma unroll
                for (int j = 0; j < RADIUS; ++j)
                    acc[p][j] = fmaf(w[p + j + 3], a[p], acc[p][j]);
        }
        __syncthreads();
    }

    // ==== epilogue: serial 4-way c-reduce in LDS (overlay on b0/b1) ====
    float* mine = &smem[t96 * 44];          // 96 x 44 floats = 4224 <= 4608
    if (cg == 3) {
#pragma unroll
        for (int j = 0; j < RADIUS; ++j) {
            float4 v = {acc[0][j], acc[1][j], acc[2][j], acc[3][j]};
            *(float4*)&mine[4 * j] = v;
        }
    }
    __syncthreads();
    if (cg == 2) {
#pragma unroll
        for (int j = 0; j < RADIUS; ++j) {
            float4 v = *(const float4*)&mine[4 * j];
            v.x += acc[0][j]; v.y += acc[1][j]; v.z += acc[2][j]; v.w += acc[3][j];
            *(float4*)&mine[4 * j] = v;
        }
    }
    __syncthreads();
    if (cg == 1) {
#pragma unroll
        for (int j = 0; j < RADIUS; ++j) {
            float4 v = *(const float4*)&mine[4 * j];
            v.x += acc[0][j]; v.y += acc[1][j]; v.z += acc[2][j]; v.w += acc[3][j];
            *(float4*)&mine[4 * j] = v;
        }
    }
    __syncthreads();
    if (cg == 0) {
#pragma unroll
        for (int j = 0; j < RADIUS; ++j) {
            float4 v = *(const float4*)&mine[4 * j];
            v.x += acc[0][j]; v.y += acc[1][j]; v.z += acc[2][j]; v.w += acc[3][j];
            *(float4*)&mine[4 * j] = v;
        }
    }
    __syncthreads();

    // ---- all threads store a disjoint j-subset of this (il, px) slot ----
    const int y = y0 + ty;
    const int xb = x0 + 4 * xc;
    float4 vI = *(const float4*)(invIg + n * HW + (size_t)y * W_ + xb);
    const int i = NIG * ig + il;
    float* ocB = out + (size_t)n * 81 * HW + (size_t)y * W_ + xb;
    const int j0  = (cg == 0) ? 0 : (cg == 1) ? 3 : (cg == 2) ? 5 : 7;
    const int cnt = (cg == 0) ? 3 : 2;
    const float* wmB = &sInvM[(ty + il) * MCOLS + 4 * xc + 3];
    for (int jj = 0; jj < cnt; ++jj) {
        int j = j0 + jj;
        float4 s = *(const float4*)&mine[4 * j];
        float4 vd, vc;
        vd.x = s.x * vI.x; vd.y = s.y * vI.y;
        vd.z = s.z * vI.z; vd.w = s.w * vI.w;
        vc.x = 1.f - vd.x * wmB[j + 0];
        vc.y = 1.f - vd.y * wmB[j + 1];
        vc.z = 1.f - vd.z * wmB[j + 2];
        vc.w = 1.f - vd.w * wmB[j + 3];
        size_t o = (size_t)(i * RADIUS + j) * HW;
        *(float4*)(ocB + o) = vc;
        *(float4*)(ocB + OUT1 + o) = vd;
    }
}

extern "C" void kernel_launch(void* const* d_in, const int* in_sizes, int n_in,
                              void* d_out, int out_size, void* d_ws, size_t ws_size,
                              hipStream_t stream) {
    const float* img = (const float*)d_in[0];
    const float* mp  = (const float*)d_in[1];
    float* out   = (float*)d_out;
    float* invI  = (float*)d_ws;                  // N_*HW
    float* invM  = invI + N_ * HW;                // N_*HW
    float* strip = invM + N_ * HW;                // N_*C_*H_*4 floats (256 KB)

    int npix = N_ * HW;
    norms_kernel<<<(npix + 255) / 256, 256, 0, stream>>>(img, mp, invI, invM, strip);

    dim3 grid(W_ / XT, H_ / YT, N_ * NIG);   // 6 x 32 x 6 = 1152 blocks
    corr_kernel<<<grid, NT, 0, stream>>>(img, mp, invI, invM, strip, out);
}

// Round 9
// 66.807 us; speedup vs baseline: 1.6796x; 1.0164x over previous
//
#include <hip/hip_runtime.h>
#include <math.h>

namespace {
constexpr int RADIUS = 9;
constexpr float EPSV = 1e-5f;
constexpr int N_ = 2, C_ = 64, H_ = 128, W_ = 192;
constexpr int HW  = H_ * W_;            // 24576
constexpr int CHW = C_ * HW;
constexpr size_t OUT1 = (size_t)N_ * 81 * HW;

constexpr int XT = 32, YT = 4;          // spatial tile
constexpr int NIG = 3;                  // i-values per block
constexpr int NT = 384;                 // 4 cg x 3 il x 4 ty x 8 xc
constexpr int MROWS = 6;                // YT + NIG - 1
constexpr int MCOLS = 44;               // cols x0-12 .. x0+31 (11 float4 chunks)
constexpr int NCH = 11;
constexpr int ROUNDS = 8;               // per round: 8 map planes + 8 img planes
constexpr int PLF = MROWS * MCOLS;      // 264 floats per map plane
constexpr int MAP_SLOTS = 528;          // 8 * 66
constexpr int IMG_SLOTS = 256;          // 8 * 32
constexpr int SLOTS_PAD = 832;          // 784 real + 48 pad (wave0 3rd DMA tail)
constexpr int BUF_F = SLOTS_PAD * 4;    // 3328 floats / buffer
constexpr int OFF_IMG = MAP_SLOTS * 4;  // 2112 floats within buffer
constexpr int OFF_INVM = 3 * BUF_F;     // 9984
constexpr int LDS_F = OFF_INVM + PLF;   // 10248 floats = 40992 B
}

__device__ __forceinline__ void load_lds16(const float* g, float* l) {
    __builtin_amdgcn_global_load_lds(
        (const __attribute__((address_space(1))) unsigned int*)(const void*)g,
        (__attribute__((address_space(3))) unsigned int*)(void*)l,
        16, 0, 0);
}

// ---------------------------------------------------------------------------
// Kernel 1: norms, 4-way c-split. block = 64 thr = 16 q4-slots x 4 c-groups.
// Emits invI, invM (per-pixel inverse L2 norms) and the left-edge replicate
// strip: strip[(n*C+c)*H+y][0..3] = map[n,c,y,0].
// ---------------------------------------------------------------------------
__global__ __launch_bounds__(64)
void norms_kernel(const float* __restrict__ img,
                  const float* __restrict__ mp,
                  float* __restrict__ invI,
                  float* __restrict__ invM,
                  float* __restrict__ strip) {
    __shared__ float4 sI[4][16], sM[4][16];
    const int tid = threadIdx.x;
    const int cg = tid >> 4;
    const int s  = tid & 15;
    const int q4 = blockIdx.x * 16 + s;          // [0, 12288)
    const int n = q4 / (HW / 4);
    const int pix = (q4 - n * (HW / 4)) * 4;
    const int y = pix / W_;
    const int x = pix - y * W_;
    const float* pi = img + (size_t)n * CHW + pix;
    const float* pm = mp  + (size_t)n * CHW + pix;
    const bool e = (x == 0);
    float* sp = strip + ((size_t)(n * C_ + cg * 16) * H_ + y) * 4;

    float4 si = {0.f, 0.f, 0.f, 0.f}, sm = {0.f, 0.f, 0.f, 0.f};
#pragma unroll
    for (int cc = 0; cc < 16; ++cc) {
        const size_t o = (size_t)(cg * 16 + cc) * HW;
        float4 a = *(const float4*)(pi + o);
        float4 b = *(const float4*)(pm + o);
        si.x = fmaf(a.x, a.x, si.x); si.y = fmaf(a.y, a.y, si.y);
        si.z = fmaf(a.z, a.z, si.z); si.w = fmaf(a.w, a.w, si.w);
        sm.x = fmaf(b.x, b.x, sm.x); sm.y = fmaf(b.y, b.y, sm.y);
        sm.z = fmaf(b.z, b.z, sm.z); sm.w = fmaf(b.w, b.w, sm.w);
        if (e) { float4 v = {b.x, b.x, b.x, b.x}; *(float4*)(sp + (size_t)cc * H_ * 4) = v; }
    }
    sI[cg][s] = si; sM[cg][s] = sm;
    __syncthreads();
    if (tid < 16) {
        float4 a = sI[0][tid], b = sM[0][tid];
#pragma unroll
        for (int g = 1; g < 4; ++g) {
            float4 u = sI[g][tid], v = sM[g][tid];
            a.x += u.x; a.y += u.y; a.z += u.z; a.w += u.w;
            b.x += v.x; b.y += v.y; b.z += v.z; b.w += v.w;
        }
        float4 vi, vm;
        vi.x = 1.f / (sqrtf(a.x) + EPSV); vi.y = 1.f / (sqrtf(a.y) + EPSV);
        vi.z = 1.f / (sqrtf(a.z) + EPSV); vi.w = 1.f / (sqrtf(a.w) + EPSV);
        vm.x = 1.f / (sqrtf(b.x) + EPSV); vm.y = 1.f / (sqrtf(b.y) + EPSV);
        vm.z = 1.f / (sqrtf(b.z) + EPSV); vm.w = 1.f / (sqrtf(b.w) + EPSV);
        *(float4*)(invI + (size_t)n * HW + pix) = vi;
        *(float4*)(invM + (size_t)n * HW + pix) = vm;
    }
}

// ---------------------------------------------------------------------------
// Kernel 2: raw correlation. ALL staging (map + img) via global_load_lds,
// triple-buffered, 2-deep prefetch, raw s_barrier + counted vmcnt (T3/T4).
//   dotRaw[p,(i,j)] = sum_c map[c, clamp(p+(i,j)-9)] * img[c, p]
//   out_diss = invI[p]*dotRaw ;  out_cos = 1 - invM[p']*out_diss
// Per-wave DMA ops/round: wave0 = 3, waves1-5 = 2 (wave-uniform).
// ---------------------------------------------------------------------------
struct SlotSrc { const float* p; int str; };

__device__ __forceinline__ SlotSrc slot_src(int s, int n, int x0, int y0, int ybase,
                                            const float* mapN, const float* imgN,
                                            const float* strip) {
    SlotSrc r;
    if (s < MAP_SLOTS) {
        int pl = s / 66, rm = s - 66 * pl, rr = rm / 11, ch = rm - 11 * rr;
        int ch0 = (pl >> 1) * 16 + (pl & 1);
        int gy = min(max(ybase + rr, 0), H_ - 1);
        int gxs = x0 - 12 + 4 * ch;
        if (gxs < 0) {                       // fully-left-OOB chunk -> strip
            r.p = strip + ((size_t)(n * C_ + ch0) * H_ + gy) * 4;
            r.str = 2 * H_ * 4;
        } else {
            r.p = mapN + (size_t)ch0 * HW + (size_t)gy * W_ + gxs;
            r.str = 2 * HW;
        }
    } else {
        int q = s - MAP_SLOTS;               // [0,256)
        int ip = q >> 5, ck = q & 31, rr = ck >> 3, k = ck & 7;
        int ch0 = (ip >> 1) * 16 + (ip & 1);
        r.p = imgN + (size_t)ch0 * HW + (size_t)(y0 + rr) * W_ + x0 + 4 * k;
        r.str = 2 * HW;
    }
    return r;
}

__global__ __launch_bounds__(NT)
void corr_kernel(const float* __restrict__ img,
                 const float* __restrict__ mp,
                 const float* __restrict__ invIg,
                 const float* __restrict__ invMg,
                 const float* __restrict__ strip,
                 float* __restrict__ out) {
    __shared__ float smem[LDS_F];
    float* const sInvM = smem + OFF_INVM;

    const int bz = blockIdx.z;             // n*3 + ig
    const int n  = bz / NIG;
    const int ig = bz - n * NIG;
    const int y0 = blockIdx.y * YT;
    const int x0 = blockIdx.x * XT;
    const int tid = threadIdx.x;
    const int cg = tid / 96;               // 0..3
    const int t96 = tid - cg * 96;
    const int il = t96 >> 5;               // 0..2
    const int r32 = t96 & 31;
    const int ty = r32 >> 3;               // 0..3
    const int xc = r32 & 7;                // 0..7
    const int ybase = y0 + NIG * ig - RADIUS;
    const bool w0 = (tid < 64);            // wave 0 (issues 3 DMA/round)

    const float* imgN = img + (size_t)n * CHW;
    const float* mapN = mp  + (size_t)n * CHW;

    // ---- invM halo (regular loads, consumed only in epilogue) ----
    if (tid < 66) {
        int r = tid / NCH, ch = tid - r * NCH;
        int gy = min(max(ybase + r, 0), H_ - 1);
        int gxs = x0 - 12 + 4 * ch;
        const float* src = invMg + n * HW + (size_t)gy * W_;
        float4 v;
        if (gxs >= 0) v = *(const float4*)(src + gxs);
        else { float s0 = src[0]; v.x = s0; v.y = s0; v.z = s0; v.w = s0; }
        *(float4*)&sInvM[r * MCOLS + 4 * ch] = v;
    }

    // ---- DMA descriptors (3 instructions/wave/round) ----
    const SlotSrc A = slot_src(tid,        n, x0, y0, ybase, mapN, imgN, strip);
    const SlotSrc B = slot_src(NT + tid,   n, x0, y0, ybase, mapN, imgN, strip);
    const SlotSrc Cc = slot_src(min(768 + tid, 783), n, x0, y0, ybase, mapN, imgN, strip);
    const int lA = 4 * tid, lB = 4 * (NT + tid), lC = 4 * (768 + tid);

    float acc[4][RADIUS];
#pragma unroll
    for (int p = 0; p < 4; ++p)
#pragma unroll
        for (int j = 0; j < RADIUS; ++j) acc[p][j] = 0.f;

    const int mapRd = (ty + il) * MCOLS + 4 * xc;
    const int imgRdBase = OFF_IMG + (cg * 2) * 32 * 4 + (ty * 8 + xc) * 4;

    // ---- prologue: rounds 0,1 in flight ----
    {
        float* nb = smem;                  // b0
        load_lds16(A.p, nb + lA);
        load_lds16(B.p, nb + lB);
        if (w0) load_lds16(Cc.p, nb + lC);
        nb = smem + BUF_F;                 // b1
        load_lds16(A.p + (size_t)A.str, nb + lA);
        load_lds16(B.p + (size_t)B.str, nb + lB);
        if (w0) load_lds16(Cc.p + (size_t)Cc.str, nb + lC);
    }

    // ---- main loop: wait own round-ri DMAs -> barrier -> issue ri+2 -> compute ri
#pragma unroll
    for (int ri = 0; ri < ROUNDS; ++ri) {
        if (ri == ROUNDS - 1) {
            asm volatile("s_waitcnt vmcnt(0)" ::: "memory");
        } else if (w0) {
            asm volatile("s_waitcnt vmcnt(3)" ::: "memory");
        } else {
            asm volatile("s_waitcnt vmcnt(2)" ::: "memory");
        }
        asm volatile("s_barrier" ::: "memory");
        if (ri + 2 < ROUNDS) {
            float* nb = smem + (size_t)((ri + 2) % 3) * BUF_F;
            load_lds16(A.p + (size_t)(ri + 2) * A.str, nb + lA);
            load_lds16(B.p + (size_t)(ri + 2) * B.str, nb + lB);
            if (w0) load_lds16(Cc.p + (size_t)(ri + 2) * Cc.str, nb + lC);
        }
        const float* cur = smem + (size_t)(ri % 3) * BUF_F;
#pragma unroll
        for (int c = 0; c < 2; ++c) {
            const float* mb = cur + (cg * 2 + c) * PLF + mapRd;
            const float4 a4 = *(const float4*)(cur + imgRdBase + c * 32 * 4);
            float w[16];
            *(float4*)&w[0]  = *(const float4*)(mb);
            *(float4*)&w[4]  = *(const float4*)(mb + 4);
            *(float4*)&w[8]  = *(const float4*)(mb + 8);
            *(float4*)&w[12] = *(const float4*)(mb + 12);
            const float a[4] = {a4.x, a4.y, a4.z, a4.w};
#pragma unroll
            for (int p = 0; p < 4; ++p)
#pragma unroll
                for (int j = 0; j < RADIUS; ++j)
                    acc[p][j] = fmaf(w[p + j + 3], a[p], acc[p][j]);
        }
    }

    // ==== epilogue: serial 4-way c-reduce in LDS (overlay on buffers) ====
    __syncthreads();
    float* mine = &smem[t96 * 44];          // 96 x 44 floats = 4224 < 3*BUF_F
    if (cg == 3) {
#pragma unroll
        for (int j = 0; j < RADIUS; ++j) {
            float4 v = {acc[0][j], acc[1][j], acc[2][j], acc[3][j]};
            *(float4*)&mine[4 * j] = v;
        }
    }
    __syncthreads();
    if (cg == 2) {
#pragma unroll
        for (int j = 0; j < RADIUS; ++j) {
            float4 v = *(const float4*)&mine[4 * j];
            v.x += acc[0][j]; v.y += acc[1][j]; v.z += acc[2][j]; v.w += acc[3][j];
            *(float4*)&mine[4 * j] = v;
        }
    }
    __syncthreads();
    if (cg == 1) {
#pragma unroll
        for (int j = 0; j < RADIUS; ++j) {
            float4 v = *(const float4*)&mine[4 * j];
            v.x += acc[0][j]; v.y += acc[1][j]; v.z += acc[2][j]; v.w += acc[3][j];
            *(float4*)&mine[4 * j] = v;
        }
    }
    __syncthreads();
    if (cg == 0) {
#pragma unroll
        for (int j = 0; j < RADIUS; ++j) {
            float4 v = *(const float4*)&mine[4 * j];
            v.x += acc[0][j]; v.y += acc[1][j]; v.z += acc[2][j]; v.w += acc[3][j];
            *(float4*)&mine[4 * j] = v;
        }
    }
    __syncthreads();

    // ---- all threads store a disjoint j-subset of this (il, px) slot ----
    const int y = y0 + ty;
    const int xb = x0 + 4 * xc;
    float4 vI = *(const float4*)(invIg + n * HW + (size_t)y * W_ + xb);
    const int i = NIG * ig + il;
    float* ocB = out + (size_t)n * 81 * HW + (size_t)y * W_ + xb;
    const int j0  = (cg == 0) ? 0 : (cg == 1) ? 3 : (cg == 2) ? 5 : 7;
    const int cnt = (cg == 0) ? 3 : 2;
    const float* wmB = &sInvM[(ty + il) * MCOLS + 4 * xc + 3];
    for (int jj = 0; jj < cnt; ++jj) {
        int j = j0 + jj;
        float4 s = *(const float4*)&mine[4 * j];
        float4 vd, vc;
        vd.x = s.x * vI.x; vd.y = s.y * vI.y;
        vd.z = s.z * vI.z; vd.w = s.w * vI.w;
        vc.x = 1.f - vd.x * wmB[j + 0];
        vc.y = 1.f - vd.y * wmB[j + 1];
        vc.z = 1.f - vd.z * wmB[j + 2];
        vc.w = 1.f - vd.w * wmB[j + 3];
        size_t o = (size_t)(i * RADIUS + j) * HW;
        *(float4*)(ocB + o) = vc;
        *(float4*)(ocB + OUT1 + o) = vd;
    }
}

extern "C" void kernel_launch(void* const* d_in, const int* in_sizes, int n_in,
                              void* d_out, int out_size, void* d_ws, size_t ws_size,
                              hipStream_t stream) {
    const float* img = (const float*)d_in[0];
    const float* mp  = (const float*)d_in[1];
    float* out   = (float*)d_out;
    float* invI  = (float*)d_ws;                  // N_*HW floats
    float* invM  = invI + N_ * HW;                // N_*HW floats
    float* strip = invM + N_ * HW;                // N_*C_*H_*4 floats (256 KB)

    norms_kernel<<<(N_ * HW / 4) / 16, 64, 0, stream>>>(img, mp, invI, invM, strip);

    dim3 grid(W_ / XT, H_ / YT, N_ * NIG);   // 6 x 32 x 6 = 1152 blocks
    corr_kernel<<<grid, NT, 0, stream>>>(img, mp, invI, invM, strip, out);
}

// Round 10
// 47.638 us; speedup vs baseline: 2.3554x; 1.4024x over previous
//
#include <hip/hip_runtime.h>
#include <math.h>

namespace {
constexpr int RADIUS = 9;
constexpr float EPSV = 1e-5f;
constexpr int N_ = 2, C_ = 64, H_ = 128, W_ = 192;
constexpr int HW  = H_ * W_;            // 24576
constexpr int CHW = C_ * HW;
constexpr size_t OUT1 = (size_t)N_ * 81 * HW;

constexpr int XT = 16, YT = 4;          // spatial tile
constexpr int NIG = 3;                  // i-values per block
constexpr int NT = 192;                 // 4 cg x (3 il x 4 ty x 4 xc)
constexpr int MROWS = 6;                // YT + NIG - 1
constexpr int MCOLS = 28;               // cols x0-12 .. x0+15 (7 float4 chunks)
constexpr int NCH = 7;
constexpr int ROUNDS = 8;               // 8 map planes per round (2 ch per cg)
constexpr int PLF = MROWS * MCOLS;      // 168 floats per map plane
constexpr int MAP_SLOTS = 336;          // 8 * 42
constexpr int SLOTS_PAD = 384;          // +48 pad (2nd-DMA tail, never read)
constexpr int BUF_F = SLOTS_PAD * 4;    // 1536 floats per buffer
constexpr int OFF_INVM = 2 * BUF_F;     // 3072
constexpr int LDS_F = OFF_INVM + PLF;   // 3240 floats = 12960 B
}

__device__ __forceinline__ void load_lds16(const float* g, float* l) {
    __builtin_amdgcn_global_load_lds(
        (const __attribute__((address_space(1))) unsigned int*)(const void*)g,
        (__attribute__((address_space(3))) unsigned int*)(void*)l,
        16, 0, 0);
}

// ---------------------------------------------------------------------------
// Kernel 1: invM (map channel-norms) + left-edge replicate strip. 8-way c-split.
// block = 64 thr = 8 cgroups x 8 q4-pixels; grid = 1536.
// ---------------------------------------------------------------------------
__global__ __launch_bounds__(64)
void norms_kernel(const float* __restrict__ mp,
                  float* __restrict__ invM,
                  float* __restrict__ strip) {
    __shared__ float4 sM[8][8];
    const int tid = threadIdx.x;
    const int cg = tid >> 3;               // 0..7 (8 channels each)
    const int s  = tid & 7;
    const int q4 = blockIdx.x * 8 + s;     // [0, 12288)
    const int n = q4 / (HW / 4);
    const int pix = (q4 - n * (HW / 4)) * 4;
    const int y = pix / W_;
    const int x = pix - y * W_;
    const float* pm = mp + (size_t)n * CHW + pix;
    const bool e = (x == 0);
    float* sp = strip + ((size_t)(n * C_ + cg * 8) * H_ + y) * 4;

    float4 sm = {0.f, 0.f, 0.f, 0.f};
#pragma unroll
    for (int cc = 0; cc < 8; ++cc) {
        float4 b = *(const float4*)(pm + (size_t)(cg * 8 + cc) * HW);
        sm.x = fmaf(b.x, b.x, sm.x); sm.y = fmaf(b.y, b.y, sm.y);
        sm.z = fmaf(b.z, b.z, sm.z); sm.w = fmaf(b.w, b.w, sm.w);
        if (e) { float4 v = {b.x, b.x, b.x, b.x}; *(float4*)(sp + (size_t)cc * H_ * 4) = v; }
    }
    sM[cg][s] = sm;
    __syncthreads();
    if (tid < 8) {
        float4 b = sM[0][tid];
#pragma unroll
        for (int g = 1; g < 8; ++g) {
            float4 v = sM[g][tid];
            b.x += v.x; b.y += v.y; b.z += v.z; b.w += v.w;
        }
        float4 vm;
        vm.x = 1.f / (sqrtf(b.x) + EPSV); vm.y = 1.f / (sqrtf(b.y) + EPSV);
        vm.z = 1.f / (sqrtf(b.z) + EPSV); vm.w = 1.f / (sqrtf(b.w) + EPSV);
        *(float4*)(invM + (size_t)n * HW + pix) = vm;   // tid<8 -> own q4 (cg=0)
    }
}

// ---------------------------------------------------------------------------
// Kernel 2: raw correlation + inline img-norm. Map staged via global_load_lds,
// double-buffered (issue ri+1 -> compute ri -> barrier drain). img from global.
//   dotRaw[p,(i,j)] = sum_c map[c, clamp(p+(i,j)-9)] * img[c, p]
//   out_diss = invI[p]*dotRaw ;  out_cos = 1 - invM[p']*out_diss
// ---------------------------------------------------------------------------
struct SlotSrc { const float* p; int str; };

__device__ __forceinline__ SlotSrc map_src(int s, int n, int x0, int ybase,
                                           const float* mapN, const float* strip) {
    int pl = s / 42, rm = s - 42 * pl, r = rm / 7, ch = rm - 7 * r;
    int ch0 = (pl >> 1) * 16 + (pl & 1);
    int gy = min(max(ybase + r, 0), H_ - 1);
    int gxs = x0 - 12 + 4 * ch;
    SlotSrc out;
    if (gxs < 0) {                          // fully-left-OOB chunk -> strip
        out.p = strip + ((size_t)(n * C_ + ch0) * H_ + gy) * 4;
        out.str = 2 * H_ * 4;
    } else {
        out.p = mapN + (size_t)ch0 * HW + (size_t)gy * W_ + gxs;
        out.str = 2 * HW;
    }
    return out;
}

__global__ __launch_bounds__(NT)
void corr_kernel(const float* __restrict__ img,
                 const float* __restrict__ mp,
                 const float* __restrict__ invMg,
                 const float* __restrict__ strip,
                 float* __restrict__ out) {
    __shared__ float smem[LDS_F];
    float* const b0 = smem;
    float* const b1 = smem + BUF_F;
    float* const sInvM = smem + OFF_INVM;

    const int bz = blockIdx.z;             // n*3 + ig
    const int n  = bz / NIG;
    const int ig = bz - n * NIG;
    const int y0 = blockIdx.y * YT;
    const int x0 = blockIdx.x * XT;
    const int tid = threadIdx.x;
    const int cg  = tid / 48;              // 0..3 (16 channels each)
    const int t48 = tid - cg * 48;
    const int il  = t48 >> 4;              // 0..2
    const int r16 = t48 & 15;
    const int ty  = r16 >> 2;              // 0..3
    const int xc  = r16 & 3;               // 0..3
    const int ybase = y0 + NIG * ig - RADIUS;

    const float* imgN = img + (size_t)n * CHW;
    const float* mapN = mp  + (size_t)n * CHW;

    // ---- invM halo (42 float4; epilogue-only) ----
    if (tid < 42) {
        int r = tid / NCH, ch = tid - r * NCH;
        int gy = min(max(ybase + r, 0), H_ - 1);
        int gxs = x0 - 12 + 4 * ch;
        const float* src = invMg + n * HW + (size_t)gy * W_;
        float4 v;
        if (gxs >= 0) v = *(const float4*)(src + gxs);
        else { float s0 = src[0]; v.x = s0; v.y = s0; v.z = s0; v.w = s0; }
        *(float4*)&sInvM[r * MCOLS + 4 * ch] = v;
    }

    // ---- DMA descriptors: 2 per thread, wave-uniform issue ----
    const SlotSrc A = map_src(tid, n, x0, ybase, mapN, strip);
    const SlotSrc B = map_src(min(NT + tid, MAP_SLOTS - 1), n, x0, ybase, mapN, strip);
    const int lA = 4 * tid, lB = 4 * (NT + tid);

    float acc[4][RADIUS];
#pragma unroll
    for (int p = 0; p < 4; ++p)
#pragma unroll
        for (int j = 0; j < RADIUS; ++j) acc[p][j] = 0.f;
    float si[4] = {0.f, 0.f, 0.f, 0.f};    // img^2 partial (this cg's 16 channels)

    const int mapRd = (ty + il) * MCOLS + 4 * xc;
    const float* imgPix = imgN + (size_t)(y0 + ty) * W_ + x0 + 4 * xc;

    // ---- prologue ----
    load_lds16(A.p, b0 + lA);
    load_lds16(B.p, b0 + lB);
    __syncthreads();

    // ---- 2-phase pipeline: DMA(ri+1) -> compute(ri) -> barrier(drain) ----
#pragma unroll
    for (int ri = 0; ri < ROUNDS; ++ri) {
        float* cur = (ri & 1) ? b1 : b0;
        float* nxt = (ri & 1) ? b0 : b1;
        if (ri + 1 < ROUNDS) {
            load_lds16(A.p + (size_t)(ri + 1) * A.str, nxt + lA);
            load_lds16(B.p + (size_t)(ri + 1) * B.str, nxt + lB);
        }
#pragma unroll
        for (int c = 0; c < 2; ++c) {
            const float* mb = cur + (cg * 2 + c) * PLF + mapRd;
            const float4 a4 = *(const float4*)(imgPix + (size_t)(cg * 16 + ri * 2 + c) * HW);
            float w[16];
            *(float4*)&w[0]  = *(const float4*)(mb);
            *(float4*)&w[4]  = *(const float4*)(mb + 4);
            *(float4*)&w[8]  = *(const float4*)(mb + 8);
            *(float4*)&w[12] = *(const float4*)(mb + 12);
            const float a[4] = {a4.x, a4.y, a4.z, a4.w};
            si[0] = fmaf(a[0], a[0], si[0]);
            si[1] = fmaf(a[1], a[1], si[1]);
            si[2] = fmaf(a[2], a[2], si[2]);
            si[3] = fmaf(a[3], a[3], si[3]);
#pragma unroll
            for (int p = 0; p < 4; ++p)
#pragma unroll
                for (int j = 0; j < RADIUS; ++j)
                    acc[p][j] = fmaf(w[p + j + 3], a[p], acc[p][j]);
        }
        __syncthreads();
    }

    // ==== epilogue: serial 4-way c-reduce in LDS (overlay on b0/b1) ====
    float* mine = &smem[t48 * 44];          // 48 x 44 floats = 2112 < 3072
    if (cg == 3) {
#pragma unroll
        for (int j = 0; j < RADIUS; ++j) {
            float4 v = {acc[0][j], acc[1][j], acc[2][j], acc[3][j]};
            *(float4*)&mine[4 * j] = v;
        }
        *(float4*)&mine[36] = *(const float4*)si;
    }
    __syncthreads();
    if (cg == 2) {
#pragma unroll
        for (int j = 0; j < RADIUS; ++j) {
            float4 v = *(const float4*)&mine[4 * j];
            v.x += acc[0][j]; v.y += acc[1][j]; v.z += acc[2][j]; v.w += acc[3][j];
            *(float4*)&mine[4 * j] = v;
        }
        float4 v = *(const float4*)&mine[36];
        v.x += si[0]; v.y += si[1]; v.z += si[2]; v.w += si[3];
        *(float4*)&mine[36] = v;
    }
    __syncthreads();
    if (cg == 1) {
#pragma unroll
        for (int j = 0; j < RADIUS; ++j) {
            float4 v = *(const float4*)&mine[4 * j];
            v.x += acc[0][j]; v.y += acc[1][j]; v.z += acc[2][j]; v.w += acc[3][j];
            *(float4*)&mine[4 * j] = v;
        }
        float4 v = *(const float4*)&mine[36];
        v.x += si[0]; v.y += si[1]; v.z += si[2]; v.w += si[3];
        *(float4*)&mine[36] = v;
    }
    __syncthreads();
    if (cg == 0) {
#pragma unroll
        for (int j = 0; j < RADIUS; ++j) {
            float4 v = *(const float4*)&mine[4 * j];
            v.x += acc[0][j]; v.y += acc[1][j]; v.z += acc[2][j]; v.w += acc[3][j];
            *(float4*)&mine[4 * j] = v;
        }
        float4 v = *(const float4*)&mine[36];
        v.x += si[0]; v.y += si[1]; v.z += si[2]; v.w += si[3];
        *(float4*)&mine[36] = v;
    }
    __syncthreads();

    // ---- all threads store a disjoint j-subset of this (il, px) slot ----
    const int y = y0 + ty;
    const int xb = x0 + 4 * xc;
    const float4 sv = *(const float4*)&mine[36];
    float4 vI;
    vI.x = 1.f / (sqrtf(sv.x) + EPSV);
    vI.y = 1.f / (sqrtf(sv.y) + EPSV);
    vI.z = 1.f / (sqrtf(sv.z) + EPSV);
    vI.w = 1.f / (sqrtf(sv.w) + EPSV);
    const int i = NIG * ig + il;
    float* ocB = out + (size_t)n * 81 * HW + (size_t)y * W_ + xb;
    const int j0  = (cg == 0) ? 0 : (cg == 1) ? 3 : (cg == 2) ? 5 : 7;
    const int cnt = (cg == 0) ? 3 : 2;
    const float* wmB = &sInvM[(ty + il) * MCOLS + 4 * xc + 3];
    for (int jj = 0; jj < cnt; ++jj) {
        int j = j0 + jj;
        float4 s = *(const float4*)&mine[4 * j];
        float4 vd, vc;
        vd.x = s.x * vI.x; vd.y = s.y * vI.y;
        vd.z = s.z * vI.z; vd.w = s.w * vI.w;
        vc.x = 1.f - vd.x * wmB[j + 0];
        vc.y = 1.f - vd.y * wmB[j + 1];
        vc.z = 1.f - vd.z * wmB[j + 2];
        vc.w = 1.f - vd.w * wmB[j + 3];
        size_t o = (size_t)(i * RADIUS + j) * HW;
        *(float4*)(ocB + o) = vc;
        *(float4*)(ocB + OUT1 + o) = vd;
    }
}

extern "C" void kernel_launch(void* const* d_in, const int* in_sizes, int n_in,
                              void* d_out, int out_size, void* d_ws, size_t ws_size,
                              hipStream_t stream) {
    const float* img = (const float*)d_in[0];
    const float* mp  = (const float*)d_in[1];
    float* out   = (float*)d_out;
    float* invM  = (float*)d_ws;                  // N_*HW floats
    float* strip = invM + N_ * HW;                // N_*C_*H_*4 floats (256 KB)

    norms_kernel<<<(N_ * HW / 4) / 8, 64, 0, stream>>>(mp, invM, strip);

    dim3 grid(W_ / XT, H_ / YT, N_ * NIG);   // 12 x 32 x 6 = 2304 blocks
    corr_kernel<<<grid, NT, 0, stream>>>(img, mp, invM, strip, out);
}